// Round 7
// baseline (42.144 us; speedup 1.0000x reference)
//
#include <hip/hip_runtime.h>
#include <math.h>

// Chamfer loss, B=8, C=3, M=N=4096, fp32 — single fused MFMA kernel.
//
// sq[m][n] = s2[m] + d2[n] - 2 s.d as a K=16 bf16 GEMM with hi/lo split:
//   A_m = [-2xh,-2xh,-2xl,-2xl | y.. | z.. | s2h,s2l,1,1]   (query rows)
//   B_n = [ xh,  xl,  xh,  xl  | y.. | z.. | 1,1,d2h,d2l]   (reference cols)
// One v_mfma_f32_32x32x16_bf16 per 32x32 tile -> sq in the accumulator.
//
// TWO directions run as separate blocks (dir in blockIdx): each block owns
// 256 rows (8 waves x 32) of one direction and scans ALL 4096 reference
// points -> the row-min completes in-block: no ws partials, no LDS atomics,
// no in-loop bwd tree. Inner 2-tile step = 2 ds_read_b128 + 2 MFMA + 16 min3.
// Epilogue: 5-step butterfly, sqrt on 2 lanes/wave, block sum, 3 atomicAdds.
//
// C layout (m74/m101): col = lane&31, row = (reg&3) + 8*(reg>>2) + 4*(lane>>5)
// A frag: row = lane&31, k = (lane>>5)*8 + j ; B frag: col = lane&31, same k.

constexpr int B = 8;
constexpr int M = 4096;   // == N; strides identical for both clouds

typedef __attribute__((ext_vector_type(8)))  short bf16x8;
typedef __attribute__((ext_vector_type(16))) float f32x16;

__device__ inline unsigned short bf16_of(float x) {   // round-to-nearest-even
    unsigned int u = __float_as_uint(x);
    u += 0x7FFFu + ((u >> 16) & 1u);
    return (unsigned short)(u >> 16);
}
__device__ inline float bf16_to_f(unsigned short h) {
    return __uint_as_float(((unsigned int)h) << 16);
}

// grid 256 = (dir<<7 | b<<4 | rg); 512 threads = 8 waves; wave w: rows rg*256+w*32..+32
__global__ __launch_bounds__(512) void chamfer_fused(
    const float* __restrict__ src,
    const float* __restrict__ dst,
    float* __restrict__ out)
{
    int bid = blockIdx.x;
    const int rg  = bid & 15; bid >>= 4;
    const int b   = bid & 7;  bid >>= 3;
    const int dir = bid;      // 0: rows=src, scan dst ; 1: rows=dst, scan src

    const float* __restrict__ qry = dir ? dst : src;   // A-side (rows)
    const float* __restrict__ ref = dir ? src : dst;   // B-side (cols)

    const int tid  = threadIdx.x;
    const int wave = tid >> 6;
    const int l31  = tid & 31;
    const int hf   = (tid >> 5) & 1;    // k-group / row-half within wave

    __shared__ __align__(16) unsigned short bstage[2][512][8];  // 16 KB
    __shared__ float bsum[16];

    // ---- augmented A fragment for this lane's row (constant across scan) ----
    bf16x8 afrag;
    {
        const int mrow = rg * 256 + wave * 32 + l31;
        const float* qb = qry + (size_t)b * 3 * M;
        const float x = qb[0 * M + mrow];
        const float y = qb[1 * M + mrow];
        const float z = qb[2 * M + mrow];
        const float s2 = x * x + y * y + z * z;
        const float xhf = bf16_to_f(bf16_of(x));
        const float yhf = bf16_to_f(bf16_of(y));
        const float zhf = bf16_to_f(bf16_of(z));
        // -2*hi exact (pow2 scale of a bf16 value)
        const unsigned short nxh = bf16_of(-2.0f * xhf), nxl = bf16_of(-2.0f * (x - xhf));
        const unsigned short nyh = bf16_of(-2.0f * yhf), nyl = bf16_of(-2.0f * (y - yhf));
        const unsigned short nzh = bf16_of(-2.0f * zhf), nzl = bf16_of(-2.0f * (z - zhf));
        const unsigned short s2h = bf16_of(s2);
        const unsigned short s2l = bf16_of(s2 - bf16_to_f(s2h));
        const unsigned short one = 0x3F80;
        bf16x8 alo, ahi;
        alo[0]=(short)nxh; alo[1]=(short)nxh; alo[2]=(short)nxl; alo[3]=(short)nxl;
        alo[4]=(short)nyh; alo[5]=(short)nyh; alo[6]=(short)nyl; alo[7]=(short)nyl;
        ahi[0]=(short)nzh; ahi[1]=(short)nzh; ahi[2]=(short)nzl; ahi[3]=(short)nzl;
        ahi[4]=(short)s2h; ahi[5]=(short)s2l; ahi[6]=(short)one; ahi[7]=(short)one;
        afrag = hf ? ahi : alo;
    }

    f32x16 fwd;
#pragma unroll
    for (int r = 0; r < 16; ++r) fwd[r] = 3.0e38f;

    const f32x16 zero = {};
    const float* rb = ref + (size_t)b * 3 * M;

    for (int ch = 0; ch < 8; ++ch) {
        __syncthreads();   // previous chunk fully consumed before overwrite
        {
            // stage 512 augmented B cols, one per thread (coalesced x/y/z loads)
            const int col = ch * 512 + tid;
            const float x = rb[0 * M + col];
            const float y = rb[1 * M + col];
            const float z = rb[2 * M + col];
            const float d2 = x * x + y * y + z * z;
            const unsigned short xh = bf16_of(x), xl = bf16_of(x - bf16_to_f(xh));
            const unsigned short yh = bf16_of(y), yl = bf16_of(y - bf16_to_f(yh));
            const unsigned short zh = bf16_of(z), zl = bf16_of(z - bf16_to_f(zh));
            const unsigned short d2h = bf16_of(d2);
            const unsigned short d2l = bf16_of(d2 - bf16_to_f(d2h));
            const unsigned short one = 0x3F80;
            bf16x8 v0, v1;
            v0[0]=(short)xh; v0[1]=(short)xl; v0[2]=(short)xh; v0[3]=(short)xl;
            v0[4]=(short)yh; v0[5]=(short)yl; v0[6]=(short)yh; v0[7]=(short)yl;
            v1[0]=(short)zh; v1[1]=(short)zl; v1[2]=(short)zh; v1[3]=(short)zl;
            v1[4]=(short)one; v1[5]=(short)one; v1[6]=(short)d2h; v1[7]=(short)d2l;
            *reinterpret_cast<bf16x8*>(&bstage[0][tid][0]) = v0;
            *reinterpret_cast<bf16x8*>(&bstage[1][tid][0]) = v1;
        }
        __syncthreads();

        // 16 tiles, 2 per step: per step 2 ds_read_b128 + 2 MFMA + 16 v_min3
#pragma unroll
        for (int i = 0; i < 8; ++i) {
            const bf16x8 bf0 = *reinterpret_cast<const bf16x8*>(&bstage[hf][i * 64 + l31][0]);
            const bf16x8 bf1 = *reinterpret_cast<const bf16x8*>(&bstage[hf][i * 64 + 32 + l31][0]);
            const f32x16 acc0 = __builtin_amdgcn_mfma_f32_32x32x16_bf16(afrag, bf0, zero, 0, 0, 0);
            const f32x16 acc1 = __builtin_amdgcn_mfma_f32_32x32x16_bf16(afrag, bf1, zero, 0, 0, 0);
#pragma unroll
            for (int r = 0; r < 16; ++r)
                fwd[r] = fminf(fwd[r], fminf(acc0[r], acc1[r]));   // v_min3_f32
        }
    }

    // butterfly min across the 32-lane col dimension (two halves = distinct rows)
#pragma unroll
    for (int r = 0; r < 16; ++r) {
        float vv = fwd[r];
        vv = fminf(vv, __shfl_xor(vv, 1));
        vv = fminf(vv, __shfl_xor(vv, 2));
        vv = fminf(vv, __shfl_xor(vv, 4));
        vv = fminf(vv, __shfl_xor(vv, 8));
        vv = fminf(vv, __shfl_xor(vv, 16));
        fwd[r] = vv;
    }

    // lanes with l31==0 (one per half-wave) hold 16 complete row-mins each
    if (l31 == 0) {
        float s = 0.0f;
#pragma unroll
        for (int r = 0; r < 16; ++r) s += sqrtf(fmaxf(fwd[r], 0.0f));
        bsum[wave * 2 + hf] = s;
    }
    __syncthreads();
    if (tid == 0) {
        float t = 0.0f;
#pragma unroll
        for (int i = 0; i < 16; ++i) t += bsum[i];
        t *= (1.0f / (float)(B * M));   // fwd /(B*M), bwd /(B*N), M==N
        atomicAdd(&out[0], t);
        atomicAdd(&out[1], t);
        atomicAdd(&out[2], t);
    }
}

extern "C" void kernel_launch(void* const* d_in, const int* in_sizes, int n_in,
                              void* d_out, int out_size, void* d_ws, size_t ws_size,
                              hipStream_t stream)
{
    const float* src = (const float*)d_in[0];   // [B,3,M]
    const float* dst = (const float*)d_in[1];   // [B,3,N]
    float* out = (float*)d_out;                 // 3 floats

    hipMemsetAsync(d_out, 0, (size_t)out_size * sizeof(float), stream);
    chamfer_fused<<<2 * B * 16, 512, 0, stream>>>(src, dst, out);
}